// Round 5
// baseline (154.029 us; speedup 1.0000x reference)
//
#include <hip/hip_runtime.h>
#include <cstdint>
#include <cstddef>

#define T_N    32768
#define N_SEG  2048
#define DSEQ   128
#define DLSTM  512
#define DX     512
#define DPROJ  1024
#define OUTW   2048
#define HSTR   520      // H row stride bytes (512+8)
#define WSCALE 2873.6827f                 // 127*sqrt(512)
#define LOG2E2 2.8853900817779268f        // 2*log2(e)
#define DEQ2   (2.8853900817779268f/(2873.6827f*127.0f))

typedef __attribute__((ext_vector_type(8))) short short8;
typedef __attribute__((ext_vector_type(4))) float f32x4;
typedef __attribute__((ext_vector_type(4))) int i32x4;

#if __has_builtin(__builtin_amdgcn_exp2f)
#define EXP2F(x) __builtin_amdgcn_exp2f(x)
#else
#define EXP2F(x) __expf((x) * 0.6931471805599453f)
#endif
#if __has_builtin(__builtin_amdgcn_rcpf)
#define RCPF(x) __builtin_amdgcn_rcpf(x)
#else
#define RCPF(x) (1.0f / (x))
#endif

__device__ inline unsigned short f2b(float f) {
  unsigned int u = __float_as_uint(f);
  unsigned int r = (u + 0x7FFFu + ((u >> 16) & 1u)) >> 16;
  return (unsigned short)r;
}

// ---------------- prep: segment boundaries + int8 weight pack (fused) ----------------
__global__ void prep_kernel(const int* __restrict__ masks,
                            int* __restrict__ seg_start, int* __restrict__ seg_end,
                            const float* __restrict__ Whh_f, const float* __restrict__ Whh_b,
                            signed char* __restrict__ W8) {
  const int bx = blockIdx.x;
  if (bx < T_N / 256) {
    int t = bx * 256 + threadIdx.x;
    int m = masks[t];
    if (t == 0 || masks[t - 1] != m) seg_start[m] = t;
    if (t == T_N - 1 || masks[t + 1] != m) seg_end[m] = t + 1;
  } else {
    int id = (bx - T_N / 256) * 256 + threadIdx.x;   // < 65536
    int dir = id >> 15;
    int rem = id & 32767;
    int g = rem >> 10;
    int kt = (rem >> 6) & 15;
    int lane = rem & 63;
    int n = g * 16 + (lane & 15);
    int k0 = kt * 32 + (lane >> 4) * 8;
    const float* W = dir ? Whh_b : Whh_f;
    signed char pkt[8];
#pragma unroll
    for (int r = 0; r < 8; ++r) {
      float w = W[(size_t)n * DLSTM + k0 + r];
      int q = (int)rintf(w * WSCALE);
      q = q > 127 ? 127 : (q < -127 ? -127 : q);
      pkt[r] = (signed char)q;
    }
    long v;
    __builtin_memcpy(&v, pkt, 8);
    *(long*)&W8[(size_t)id * 8] = v;
  }
}

// ---------------- counting sort of segments by length, descending ----------------
__global__ __launch_bounds__(1024) void csort_kernel(const int* __restrict__ seg_start,
                                                     const int* __restrict__ seg_end,
                                                     int* __restrict__ sorted_ids) {
  __shared__ int A_[2048];
  __shared__ int B_[2048];
  const int tid = threadIdx.x;
  for (int i = tid; i < 2048; i += 1024) A_[i] = 0;
  __syncthreads();
  for (int i = tid; i < N_SEG; i += 1024) {
    int len = seg_end[i] - seg_start[i];
    int b = len < 2047 ? len : 2047;
    atomicAdd(&A_[b], 1);
  }
  __syncthreads();
  int* src = A_;
  int* dst = B_;
  for (int d = 1; d < 2048; d <<= 1) {
    for (int i = tid; i < 2048; i += 1024) {
      int v = src[i];
      if (i + d < 2048) v += src[i + d];
      dst[i] = v;
    }
    __syncthreads();
    int* t_ = src; src = dst; dst = t_;
  }
  for (int i = tid; i < 2048; i += 1024)
    dst[i] = (i + 1 < 2048) ? src[i + 1] : 0;
  __syncthreads();
  for (int i = tid; i < N_SEG; i += 1024) {
    int len = seg_end[i] - seg_start[i];
    int b = len < 2047 ? len : 2047;
    int pos = atomicAdd(&dst[b], 1);
    sorted_ids[pos] = i;
  }
}

// ---------------- pre-GEMM: K=128 one-shot, C(bf16) = (A @ [B0;B1]^T + bias)*oscale ----------------
// grid (M/128, 8): lin = mtile + 256*ntile -> lin%8 = mtile%8: all n-tiles of an
// m-tile land on the same XCD (A tile stays L2-resident).
__global__ __launch_bounds__(256, 2) void gemm_k128_kernel(
    const float* __restrict__ A, const float* __restrict__ B0, const float* __restrict__ B1,
    const float* __restrict__ bias0, const float* __restrict__ bias1,
    unsigned short* __restrict__ C, float oscale) {
  __shared__ unsigned short As[128][136];
  const int tid = threadIdx.x;
  const int m0 = blockIdx.x * 128, n0 = blockIdx.y * 128;
  const int wave = tid >> 6, lane = tid & 63;
  const int wm = (wave >> 1) * 64, wn = (wave & 1) * 64;
  const int rowA = lane & 15, kgrp = lane >> 4;
  const int lrow = tid >> 1, lk = (tid & 1) * 64;

  // stage A tile (coalesced f32 -> bf16 -> LDS)
  {
    const float* ap = A + (size_t)(m0 + lrow) * 128 + lk;
    unsigned short tmp[64];
#pragma unroll
    for (int q = 0; q < 16; ++q) {
      float4 v = *(const float4*)(ap + q * 4);
      tmp[q * 4 + 0] = f2b(v.x); tmp[q * 4 + 1] = f2b(v.y);
      tmp[q * 4 + 2] = f2b(v.z); tmp[q * 4 + 3] = f2b(v.w);
    }
#pragma unroll
    for (int q = 0; q < 8; ++q) *(short8*)&As[lrow][lk + q * 8] = *(short8*)&tmp[q * 8];
  }
  __syncthreads();

  f32x4 acc[4][4];
#pragma unroll
  for (int i = 0; i < 4; ++i)
#pragma unroll
    for (int j = 0; j < 4; ++j) acc[i][j] = (f32x4){0.f, 0.f, 0.f, 0.f};

  const int nb = n0 + wn + rowA;   // B row for this lane (per nt: +nt*16)
#pragma unroll
  for (int kt = 0; kt < 4; ++kt) {
    short8 bf[4];
#pragma unroll
    for (int nt = 0; nt < 4; ++nt) {
      int n = nb + nt * 16;
      const float* bp = (n < 512) ? (B0 + (size_t)n * 128) : (B1 + (size_t)(n - 512) * 128);
      bp += kt * 32 + kgrp * 8;
      float4 v0 = *(const float4*)bp;
      float4 v1 = *(const float4*)(bp + 4);
      unsigned short pb[8] = {f2b(v0.x), f2b(v0.y), f2b(v0.z), f2b(v0.w),
                              f2b(v1.x), f2b(v1.y), f2b(v1.z), f2b(v1.w)};
      bf[nt] = *(short8*)pb;
    }
    short8 af[4];
#pragma unroll
    for (int mt = 0; mt < 4; ++mt)
      af[mt] = *(const short8*)&As[wm + mt * 16 + rowA][kt * 32 + kgrp * 8];
#pragma unroll
    for (int mt = 0; mt < 4; ++mt)
#pragma unroll
      for (int nt = 0; nt < 4; ++nt)
        acc[mt][nt] = __builtin_amdgcn_mfma_f32_16x16x32_bf16(af[mt], bf[nt], acc[mt][nt], 0, 0, 0);
  }

#pragma unroll
  for (int nt = 0; nt < 4; ++nt) {
    int n = nb + nt * 16;
    float bv = (n < 512) ? bias0[n] : bias1[n - 512];
#pragma unroll
    for (int mt = 0; mt < 4; ++mt) {
#pragma unroll
      for (int r = 0; r < 4; ++r) {
        int m = m0 + wm + mt * 16 + kgrp * 4 + r;
        C[(size_t)m * 1024 + n] = f2b((acc[mt][nt][r] + bv) * oscale);
      }
    }
  }
}

// ---------------- proj GEMM (K=512, f32 out): C = A @ B^T + bias ----------------
__global__ __launch_bounds__(256) void gemm_bt_kernel(
    const float* __restrict__ A, const float* __restrict__ B0,
    const float* __restrict__ bias0, int K, float* __restrict__ C, int ldc) {
  __shared__ unsigned short As[128][40];
  __shared__ unsigned short Bs[128][40];
  const int tid = threadIdx.x;
  const int m0 = blockIdx.x * 128, n0 = blockIdx.y * 128;
  const int wave = tid >> 6, lane = tid & 63;
  const int wm = (wave >> 1) * 64, wn = (wave & 1) * 64;
  const int rowA = lane & 15, kgrp = lane >> 4;
  const int lrow = tid >> 1, lkc = (tid & 1) * 16;

  f32x4 acc[4][4];
#pragma unroll
  for (int i = 0; i < 4; ++i)
#pragma unroll
    for (int j = 0; j < 4; ++j) acc[i][j] = (f32x4){0.f, 0.f, 0.f, 0.f};

  for (int k0 = 0; k0 < K; k0 += 32) {
    __syncthreads();
    {
      const float* ap = A + (size_t)(m0 + lrow) * K + k0 + lkc;
      unsigned short pa[16];
#pragma unroll
      for (int q = 0; q < 4; ++q) {
        float4 v = *(const float4*)(ap + q * 4);
        pa[q * 4 + 0] = f2b(v.x); pa[q * 4 + 1] = f2b(v.y);
        pa[q * 4 + 2] = f2b(v.z); pa[q * 4 + 3] = f2b(v.w);
      }
      *(short8*)&As[lrow][lkc] = *(short8*)&pa[0];
      *(short8*)&As[lrow][lkc + 8] = *(short8*)&pa[8];

      const float* bp = B0 + (size_t)(n0 + lrow) * K + k0 + lkc;
      unsigned short pb[16];
#pragma unroll
      for (int q = 0; q < 4; ++q) {
        float4 v = *(const float4*)(bp + q * 4);
        pb[q * 4 + 0] = f2b(v.x); pb[q * 4 + 1] = f2b(v.y);
        pb[q * 4 + 2] = f2b(v.z); pb[q * 4 + 3] = f2b(v.w);
      }
      *(short8*)&Bs[lrow][lkc] = *(short8*)&pb[0];
      *(short8*)&Bs[lrow][lkc + 8] = *(short8*)&pb[8];
    }
    __syncthreads();
    short8 af[4], bf[4];
#pragma unroll
    for (int mt = 0; mt < 4; ++mt) af[mt] = *(const short8*)&As[wm + mt * 16 + rowA][kgrp * 8];
#pragma unroll
    for (int nt = 0; nt < 4; ++nt) bf[nt] = *(const short8*)&Bs[wn + nt * 16 + rowA][kgrp * 8];
#pragma unroll
    for (int mt = 0; mt < 4; ++mt)
#pragma unroll
      for (int nt = 0; nt < 4; ++nt)
        acc[mt][nt] = __builtin_amdgcn_mfma_f32_16x16x32_bf16(af[mt], bf[nt], acc[mt][nt], 0, 0, 0);
  }

#pragma unroll
  for (int mt = 0; mt < 4; ++mt)
#pragma unroll
    for (int nt = 0; nt < 4; ++nt) {
      int n = n0 + wn + nt * 16 + rowA;
      float bv = bias0[n];
#pragma unroll
      for (int r = 0; r < 4; ++r) {
        int m = m0 + wm + mt * 16 + kgrp * 4 + r;
        C[(size_t)m * ldc + n] = acc[mt][nt][r] + bv;
      }
    }
}

// ---------------- scan: transposed i8 MFMA, counted-wait barrier, depth-2 prefetch ----------------
// grid (128, 2), block 512 (8 waves). Wave w owns dims [w*64, w*64+64).
__global__ __launch_bounds__(512, 2) void scan_i8t_kernel(
    const unsigned short* __restrict__ pre,   // [T][1024] bf16, pre-scaled by 2*log2(e)
    const signed char* __restrict__ W8,
    const int* __restrict__ sorted_ids, const int* __restrict__ seg_start_g,
    const int* __restrict__ seg_end_g, float* __restrict__ out) {
  const int dir = blockIdx.y, bb = blockIdx.x;
  const int tid = threadIdx.x;
  const int wave = tid >> 6, lane = tid & 63;
  const int chain = lane & 15, kgrp = lane >> 4;
  const int dbase = wave * 64;

  __shared__ signed char H[2][16][HSTR];
  __shared__ int s_start[16], s_len[16], s_sid[16];

  if (tid < 16) {
    int sid = sorted_ids[bb * 16 + tid];
    s_sid[tid] = sid;
    int st = seg_start_g[sid];
    s_start[tid] = st;
    s_len[tid] = seg_end_g[sid] - st;
  }
  for (int i = tid; i < 16 * 128; i += 512) {
    int r = i >> 7, o = (i & 127) << 2;
    *(int*)&H[0][r][o] = 0;
  }

  long wreg[4][16];
  {
    const signed char* wb = W8 + (((size_t)(dir * 32 + wave * 4)) * 16) * 512 + (size_t)lane * 8;
#pragma unroll
    for (int mt = 0; mt < 4; ++mt)
#pragma unroll
      for (int kt = 0; kt < 16; ++kt)
        wreg[mt][kt] = *(const long*)(wb + (size_t)(mt * 16 + kt) * 512);
  }
  __syncthreads();

  int maxlen = 0;
#pragma unroll
  for (int c = 0; c < 16; ++c) maxlen = maxlen > s_len[c] ? maxlen : s_len[c];
  const int myLen = s_len[chain], myStart = s_start[chain];
  const int sid = s_sid[chain];

  const unsigned short* __restrict__ pb = pre + (size_t)dir * 512 + dbase + kgrp * 4;

  uint2 pu0[4], pu1[4];
  {
    int t = dir ? (myStart + myLen - 1) : myStart;
    const unsigned short* p = pb + (size_t)t * 1024;
#pragma unroll
    for (int mt = 0; mt < 4; ++mt) pu0[mt] = *(const uint2*)(p + mt * 16);
  }
  {
    int sn = (1 < myLen) ? 1 : (myLen - 1);
    int t = dir ? (myStart + myLen - 1 - sn) : (myStart + sn);
    const unsigned short* p = pb + (size_t)t * 1024;
#pragma unroll
    for (int mt = 0; mt < 4; ++mt) pu1[mt] = *(const uint2*)(p + mt * 16);
  }

  float pool[4][4];
#pragma unroll
  for (int mt = 0; mt < 4; ++mt)
#pragma unroll
    for (int r = 0; r < 4; ++r) pool[mt][r] = 0.f;

  int cur = 0;
  for (int s = 0; s < maxlen; ++s) {
    // prefetch pre for step s+2 (stays in flight across the raw barrier)
    uint2 pu2[4];
    {
      int sn = (s + 2 < myLen) ? (s + 2) : (myLen - 1);
      int t = dir ? (myStart + myLen - 1 - sn) : (myStart + sn);
      const unsigned short* p = pb + (size_t)t * 1024;
#pragma unroll
      for (int mt = 0; mt < 4; ++mt) pu2[mt] = *(const uint2*)(p + mt * 16);
    }

    i32x4 acc[4];
#pragma unroll
    for (int mt = 0; mt < 4; ++mt) acc[mt] = (i32x4){0, 0, 0, 0};
#pragma unroll
    for (int kt = 0; kt < 16; ++kt) {
      long hb = *(const long*)&H[cur][chain][kt * 32 + kgrp * 8];
#pragma unroll
      for (int mt = 0; mt < 4; ++mt)
        acc[mt] = __builtin_amdgcn_mfma_i32_16x16x32_i8(wreg[mt][kt], hb, acc[mt], 0, 0, 0);
    }

    const float msk = (s < myLen) ? 1.f : 0.f;
#pragma unroll
    for (int mt = 0; mt < 4; ++mt) {
      float p2[4];
      p2[0] = __uint_as_float(pu0[mt].x << 16);
      p2[1] = __uint_as_float(pu0[mt].x & 0xFFFF0000u);
      p2[2] = __uint_as_float(pu0[mt].y << 16);
      p2[3] = __uint_as_float(pu0[mt].y & 0xFFFF0000u);
      int q[4];
#pragma unroll
      for (int r = 0; r < 4; ++r) {
        float x2 = fmaf((float)acc[mt][r], DEQ2, p2[r]);
        float e = EXP2F(x2);
        float rc = RCPF(e + 1.f);
        float h = fmaf(-2.f, rc, 1.f);
        pool[mt][r] = fmaf(h, msk, pool[mt][r]);
        q[r] = (int)rintf(fmaf(-254.f, rc, 127.f));
      }
      unsigned int pk = (unsigned)(q[0] & 255) | ((unsigned)(q[1] & 255) << 8) |
                        ((unsigned)(q[2] & 255) << 16) | ((unsigned)q[3] << 24);
      *(unsigned int*)&H[cur ^ 1][chain][dbase + mt * 16 + kgrp * 4] = pk;
    }
    // counted-wait barrier: drain LDS writes only; global prefetch stays in flight
    asm volatile("s_waitcnt lgkmcnt(0)" ::: "memory");
    __builtin_amdgcn_s_barrier();
    __builtin_amdgcn_sched_barrier(0);
#pragma unroll
    for (int mt = 0; mt < 4; ++mt) { pu0[mt] = pu1[mt]; pu1[mt] = pu2[mt]; }
    cur ^= 1;
  }

  const float inv = 1.0f / (float)myLen;
  float* op = out + (size_t)sid * OUTW + DPROJ + dir * DLSTM + dbase + kgrp * 4;
#pragma unroll
  for (int mt = 0; mt < 4; ++mt)
    *(float4*)(op + mt * 16) = make_float4(pool[mt][0] * inv, pool[mt][1] * inv,
                                           pool[mt][2] * inv, pool[mt][3] * inv);
}

extern "C" void kernel_launch(void* const* d_in, const int* in_sizes, int n_in,
                              void* d_out, int out_size, void* d_ws, size_t ws_size,
                              hipStream_t stream) {
  const float* x     = (const float*)d_in[0];
  const float* seqs  = (const float*)d_in[1];
  const int*   masks = (const int*)d_in[2];
  const float* Wih_f = (const float*)d_in[3];
  const float* Whh_f = (const float*)d_in[4];
  const float* b_f   = (const float*)d_in[5];
  const float* Wih_b = (const float*)d_in[6];
  const float* Whh_b = (const float*)d_in[7];
  const float* b_b   = (const float*)d_in[8];
  const float* Wx    = (const float*)d_in[9];
  const float* bx    = (const float*)d_in[10];
  float* out = (float*)d_out;

  char* ws = (char*)d_ws;
  const size_t pre_bytes = (size_t)T_N * 1024 * 2;   // 67.1 MB
  const size_t w8_bytes  = (size_t)2 * 512 * 512;    // 0.5 MB
  unsigned short* pre = (unsigned short*)ws;
  signed char* W8     = (signed char*)(ws + pre_bytes);
  int* seg_start      = (int*)(ws + pre_bytes + w8_bytes);
  int* seg_end        = seg_start + N_SEG;
  int* sorted_ids     = seg_end + N_SEG;

  prep_kernel<<<T_N / 256 + 256, 256, 0, stream>>>(masks, seg_start, seg_end, Whh_f, Whh_b, W8);
  csort_kernel<<<1, 1024, 0, stream>>>(seg_start, seg_end, sorted_ids);
  // pre = (seqs @ [Wih_f;Wih_b]^T + [b_f;b_b]) * 2*log2(e), bf16 out
  gemm_k128_kernel<<<dim3(T_N / 128, 8), 256, 0, stream>>>(
      seqs, Wih_f, Wih_b, b_f, b_b, pre, LOG2E2);
  // out[:,0:1024] = x @ Wx^T + bx, f32 out
  gemm_bt_kernel<<<dim3(N_SEG / 128, DPROJ / 128), 256, 0, stream>>>(
      x, Wx, bx, DX, out, OUTW);
  scan_i8t_kernel<<<dim3(N_SEG / 16, 2), 512, 0, stream>>>(
      pre, W8, sorted_ids, seg_start, seg_end, out);
}

// Round 6
// 130.184 us; speedup vs baseline: 1.1832x; 1.1832x over previous
//
#include <hip/hip_runtime.h>
#include <cstdint>
#include <cstddef>

#define T_N    32768
#define N_SEG  2048
#define DSEQ   128
#define DLSTM  512
#define DX     512
#define DPROJ  1024
#define OUTW   2048
#define HSTR   520      // H row stride bytes (512+8)
#define WSCALE 2873.6827f                 // 127*sqrt(512)
#define LOG2E2 2.8853900817779268f        // 2*log2(e)
#define DEQ2   (2.8853900817779268f/(2873.6827f*127.0f))

typedef __attribute__((ext_vector_type(8))) short short8;
typedef __attribute__((ext_vector_type(4))) float f32x4;
typedef __attribute__((ext_vector_type(4))) int i32x4;

#if __has_builtin(__builtin_amdgcn_exp2f)
#define EXP2F(x) __builtin_amdgcn_exp2f(x)
#else
#define EXP2F(x) __expf((x) * 0.6931471805599453f)
#endif
#if __has_builtin(__builtin_amdgcn_rcpf)
#define RCPF(x) __builtin_amdgcn_rcpf(x)
#else
#define RCPF(x) (1.0f / (x))
#endif

__device__ inline unsigned short f2b(float f) {
  unsigned int u = __float_as_uint(f);
  unsigned int r = (u + 0x7FFFu + ((u >> 16) & 1u)) >> 16;
  return (unsigned short)r;
}
// packed f32x2 -> bf16x2 (RNE), dst.lo=cvt(a), dst.hi=cvt(b)
__device__ inline unsigned int cvtpk(float a, float b) {
  unsigned int r;
  asm("v_cvt_pk_bf16_f32 %0, %1, %2" : "=v"(r) : "v"(a), "v"(b));
  return r;
}

// ---------------- prep: seg bounds + int8 W_hh pack + bf16 W_ih frag pack ----------------
// blocks [0,128): seg bounds. [128,384): W8 pack. [384,400): WF pack.
__global__ void prep_kernel(const int* __restrict__ masks,
                            int* __restrict__ seg_start, int* __restrict__ seg_end,
                            const float* __restrict__ Whh_f, const float* __restrict__ Whh_b,
                            const float* __restrict__ Wih_f, const float* __restrict__ Wih_b,
                            signed char* __restrict__ W8, unsigned short* __restrict__ WF) {
  const int bx = blockIdx.x;
  if (bx < T_N / 256) {
    int t = bx * 256 + threadIdx.x;
    int m = masks[t];
    if (t == 0 || masks[t - 1] != m) seg_start[m] = t;
    if (t == T_N - 1 || masks[t + 1] != m) seg_end[m] = t + 1;
  } else if (bx < T_N / 256 + 256) {
    int id = (bx - T_N / 256) * 256 + threadIdx.x;   // < 65536
    int dir = id >> 15;
    int rem = id & 32767;
    int g = rem >> 10;
    int kt = (rem >> 6) & 15;
    int lane = rem & 63;
    int n = g * 16 + (lane & 15);
    int k0 = kt * 32 + (lane >> 4) * 8;
    const float* W = dir ? Whh_b : Whh_f;
    signed char pkt[8];
#pragma unroll
    for (int r = 0; r < 8; ++r) {
      float w = W[(size_t)n * DLSTM + k0 + r];
      int q = (int)rintf(w * WSCALE);
      q = q > 127 ? 127 : (q < -127 ? -127 : q);
      pkt[r] = (signed char)q;
    }
    long v;
    __builtin_memcpy(&v, pkt, 8);
    *(long*)&W8[(size_t)id * 8] = v;
  } else {
    // WF: A-frag packed [g(64)][lane(64)][kt(4)][8 bf16]; n=g*16+(lane&15), k=kt*32+(lane>>4)*8+j
    int gl = (bx - (T_N / 256 + 256)) * 256 + threadIdx.x;   // < 4096
    int g = gl >> 6, lane = gl & 63;
    int n = g * 16 + (lane & 15);
    const float* src = (n < 512) ? (Wih_f + (size_t)n * DSEQ)
                                 : (Wih_b + (size_t)(n - 512) * DSEQ);
#pragma unroll
    for (int kt = 0; kt < 4; ++kt) {
      int k0 = kt * 32 + (lane >> 4) * 8;
      float4 v0 = *(const float4*)(src + k0);
      float4 v1 = *(const float4*)(src + k0 + 4);
      unsigned int w[4] = {cvtpk(v0.x, v0.y), cvtpk(v0.z, v0.w),
                           cvtpk(v1.x, v1.y), cvtpk(v1.z, v1.w)};
      *(uint4*)&WF[(size_t)((gl << 2) + kt) * 8] = *(uint4*)w;
    }
  }
}

// ---------------- counting sort of segments by length, descending ----------------
__global__ __launch_bounds__(1024) void csort_kernel(const int* __restrict__ seg_start,
                                                     const int* __restrict__ seg_end,
                                                     int* __restrict__ sorted_ids) {
  __shared__ int A_[2048];
  __shared__ int B_[2048];
  const int tid = threadIdx.x;
  for (int i = tid; i < 2048; i += 1024) A_[i] = 0;
  __syncthreads();
  for (int i = tid; i < N_SEG; i += 1024) {
    int len = seg_end[i] - seg_start[i];
    int b = len < 2047 ? len : 2047;
    atomicAdd(&A_[b], 1);
  }
  __syncthreads();
  int* src = A_;
  int* dst = B_;
  for (int d = 1; d < 2048; d <<= 1) {
    for (int i = tid; i < 2048; i += 1024) {
      int v = src[i];
      if (i + d < 2048) v += src[i + d];
      dst[i] = v;
    }
    __syncthreads();
    int* t_ = src; src = dst; dst = t_;
  }
  for (int i = tid; i < 2048; i += 1024)
    dst[i] = (i + 1 < 2048) ? src[i + 1] : 0;
  __syncthreads();
  for (int i = tid; i < N_SEG; i += 1024) {
    int len = seg_end[i] - seg_start[i];
    int b = len < 2047 ? len : 2047;
    int pos = atomicAdd(&dst[b], 1);
    sorted_ids[pos] = i;
  }
}

// ---------------- pre-GEMM v2: operand-swapped, LDS-free ----------------
// pre[m][n] = (seqs[m] . W_ih[n] + b[n]) * LOG2E2, bf16.  512 blocks x 64 m-rows.
// Wave w owns n in [w*256, w*256+256), 2 passes of 128. D rows = n, D cols = m.
__global__ __launch_bounds__(256, 2) void gemm_pre_kernel(
    const float* __restrict__ seqs, const unsigned short* __restrict__ WF,
    const float* __restrict__ b_f, const float* __restrict__ b_b,
    unsigned short* __restrict__ pre) {
  const int tid = threadIdx.x;
  const int wave = tid >> 6, lane = tid & 63;
  const int m0 = blockIdx.x * 64;
  const int kgrp = lane >> 4;

  // B-frags: seqs rows (col index = lane&15), held across both passes
  short8 bfr[4][4];   // [mt][kt]
#pragma unroll
  for (int mt = 0; mt < 4; ++mt) {
    const float* sp = seqs + (size_t)(m0 + mt * 16 + (lane & 15)) * DSEQ;
#pragma unroll
    for (int kt = 0; kt < 4; ++kt) {
      int k0 = kt * 32 + kgrp * 8;
      float4 v0 = *(const float4*)(sp + k0);
      float4 v1 = *(const float4*)(sp + k0 + 4);
      unsigned int w[4] = {cvtpk(v0.x, v0.y), cvtpk(v0.z, v0.w),
                           cvtpk(v1.x, v1.y), cvtpk(v1.z, v1.w)};
      bfr[mt][kt] = *(short8*)w;
    }
  }

#pragma unroll
  for (int pass = 0; pass < 2; ++pass) {
    f32x4 acc[8][4];
#pragma unroll
    for (int nf = 0; nf < 8; ++nf)
#pragma unroll
      for (int mt = 0; mt < 4; ++mt) acc[nf][mt] = (f32x4){0.f, 0.f, 0.f, 0.f};

#pragma unroll
    for (int nf = 0; nf < 8; ++nf) {
      const int g = wave * 16 + pass * 8 + nf;
      short8 wf[4];
      const unsigned short* wp = WF + (size_t)((g * 64 + lane) << 2) * 8;
#pragma unroll
      for (int kt = 0; kt < 4; ++kt) wf[kt] = *(const short8*)(wp + kt * 8);
#pragma unroll
      for (int kt = 0; kt < 4; ++kt)
#pragma unroll
        for (int mt = 0; mt < 4; ++mt)
          acc[nf][mt] = __builtin_amdgcn_mfma_f32_16x16x32_bf16(wf[kt], bfr[mt][kt],
                                                                acc[nf][mt], 0, 0, 0);
    }

    // epilogue: n = g*16 + kgrp*4 + r, m = m0 + mt*16 + (lane&15)
#pragma unroll
    for (int nf = 0; nf < 8; ++nf) {
      const int g = wave * 16 + pass * 8 + nf;
      const float* bsrc = (g < 32) ? (b_f + g * 16) : (b_b + (g - 32) * 16);
      float4 bv = *(const float4*)(bsrc + kgrp * 4);
      float bs[4] = {bv.x * LOG2E2, bv.y * LOG2E2, bv.z * LOG2E2, bv.w * LOG2E2};
#pragma unroll
      for (int mt = 0; mt < 4; ++mt) {
        float v0 = fmaf(acc[nf][mt][0], LOG2E2, bs[0]);
        float v1 = fmaf(acc[nf][mt][1], LOG2E2, bs[1]);
        float v2 = fmaf(acc[nf][mt][2], LOG2E2, bs[2]);
        float v3 = fmaf(acc[nf][mt][3], LOG2E2, bs[3]);
        unsigned int w[2] = {cvtpk(v0, v1), cvtpk(v2, v3)};
        size_t m = (size_t)(m0 + mt * 16 + (lane & 15));
        *(uint2*)&pre[m * 1024 + g * 16 + kgrp * 4] = *(uint2*)w;
      }
    }
  }
}

// ---------------- proj GEMM (K=512, f32 out): C = A @ B^T + bias ----------------
__global__ __launch_bounds__(256) void gemm_bt_kernel(
    const float* __restrict__ A, const float* __restrict__ B0,
    const float* __restrict__ bias0, int K, float* __restrict__ C, int ldc) {
  __shared__ unsigned short As[128][40];
  __shared__ unsigned short Bs[128][40];
  const int tid = threadIdx.x;
  const int m0 = blockIdx.x * 128, n0 = blockIdx.y * 128;
  const int wave = tid >> 6, lane = tid & 63;
  const int wm = (wave >> 1) * 64, wn = (wave & 1) * 64;
  const int rowA = lane & 15, kgrp = lane >> 4;
  const int lrow = tid >> 1, lkc = (tid & 1) * 16;

  f32x4 acc[4][4];
#pragma unroll
  for (int i = 0; i < 4; ++i)
#pragma unroll
    for (int j = 0; j < 4; ++j) acc[i][j] = (f32x4){0.f, 0.f, 0.f, 0.f};

  for (int k0 = 0; k0 < K; k0 += 32) {
    __syncthreads();
    {
      const float* ap = A + (size_t)(m0 + lrow) * K + k0 + lkc;
      unsigned short pa[16];
#pragma unroll
      for (int q = 0; q < 4; ++q) {
        float4 v = *(const float4*)(ap + q * 4);
        pa[q * 4 + 0] = f2b(v.x); pa[q * 4 + 1] = f2b(v.y);
        pa[q * 4 + 2] = f2b(v.z); pa[q * 4 + 3] = f2b(v.w);
      }
      *(short8*)&As[lrow][lkc] = *(short8*)&pa[0];
      *(short8*)&As[lrow][lkc + 8] = *(short8*)&pa[8];

      const float* bp = B0 + (size_t)(n0 + lrow) * K + k0 + lkc;
      unsigned short pb[16];
#pragma unroll
      for (int q = 0; q < 4; ++q) {
        float4 v = *(const float4*)(bp + q * 4);
        pb[q * 4 + 0] = f2b(v.x); pb[q * 4 + 1] = f2b(v.y);
        pb[q * 4 + 2] = f2b(v.z); pb[q * 4 + 3] = f2b(v.w);
      }
      *(short8*)&Bs[lrow][lkc] = *(short8*)&pb[0];
      *(short8*)&Bs[lrow][lkc + 8] = *(short8*)&pb[8];
    }
    __syncthreads();
    short8 af[4], bf[4];
#pragma unroll
    for (int mt = 0; mt < 4; ++mt) af[mt] = *(const short8*)&As[wm + mt * 16 + rowA][kgrp * 8];
#pragma unroll
    for (int nt = 0; nt < 4; ++nt) bf[nt] = *(const short8*)&Bs[wn + nt * 16 + rowA][kgrp * 8];
#pragma unroll
    for (int mt = 0; mt < 4; ++mt)
#pragma unroll
      for (int nt = 0; nt < 4; ++nt)
        acc[mt][nt] = __builtin_amdgcn_mfma_f32_16x16x32_bf16(af[mt], bf[nt], acc[mt][nt], 0, 0, 0);
  }

#pragma unroll
  for (int mt = 0; mt < 4; ++mt)
#pragma unroll
    for (int nt = 0; nt < 4; ++nt) {
      int n = n0 + wn + nt * 16 + rowA;
      float bv = bias0[n];
#pragma unroll
      for (int r = 0; r < 4; ++r) {
        int m = m0 + wm + mt * 16 + kgrp * 4 + r;
        C[(size_t)m * ldc + n] = acc[mt][nt][r] + bv;
      }
    }
}

// ---------------- scan: transposed i8 MFMA, counted-wait barrier, depth-2 prefetch ----------------
__global__ __launch_bounds__(512, 2) void scan_i8t_kernel(
    const unsigned short* __restrict__ pre,   // [T][1024] bf16, pre-scaled by 2*log2(e)
    const signed char* __restrict__ W8,
    const int* __restrict__ sorted_ids, const int* __restrict__ seg_start_g,
    const int* __restrict__ seg_end_g, float* __restrict__ out) {
  const int dir = blockIdx.y, bb = blockIdx.x;
  const int tid = threadIdx.x;
  const int wave = tid >> 6, lane = tid & 63;
  const int chain = lane & 15, kgrp = lane >> 4;
  const int dbase = wave * 64;

  __shared__ signed char H[2][16][HSTR];
  __shared__ int s_start[16], s_len[16], s_sid[16];

  if (tid < 16) {
    int sid = sorted_ids[bb * 16 + tid];
    s_sid[tid] = sid;
    int st = seg_start_g[sid];
    s_start[tid] = st;
    s_len[tid] = seg_end_g[sid] - st;
  }
  for (int i = tid; i < 16 * 128; i += 512) {
    int r = i >> 7, o = (i & 127) << 2;
    *(int*)&H[0][r][o] = 0;
  }

  long wreg[4][16];
  {
    const signed char* wb = W8 + (((size_t)(dir * 32 + wave * 4)) * 16) * 512 + (size_t)lane * 8;
#pragma unroll
    for (int mt = 0; mt < 4; ++mt)
#pragma unroll
      for (int kt = 0; kt < 16; ++kt)
        wreg[mt][kt] = *(const long*)(wb + (size_t)(mt * 16 + kt) * 512);
  }
  __syncthreads();

  int maxlen = 0;
#pragma unroll
  for (int c = 0; c < 16; ++c) maxlen = maxlen > s_len[c] ? maxlen : s_len[c];
  const int myLen = s_len[chain], myStart = s_start[chain];
  const int sid = s_sid[chain];

  const unsigned short* __restrict__ pb = pre + (size_t)dir * 512 + dbase + kgrp * 4;

  uint2 pu0[4], pu1[4];
  {
    int t = dir ? (myStart + myLen - 1) : myStart;
    const unsigned short* p = pb + (size_t)t * 1024;
#pragma unroll
    for (int mt = 0; mt < 4; ++mt) pu0[mt] = *(const uint2*)(p + mt * 16);
  }
  {
    int sn = (1 < myLen) ? 1 : (myLen - 1);
    int t = dir ? (myStart + myLen - 1 - sn) : (myStart + sn);
    const unsigned short* p = pb + (size_t)t * 1024;
#pragma unroll
    for (int mt = 0; mt < 4; ++mt) pu1[mt] = *(const uint2*)(p + mt * 16);
  }

  float pool[4][4];
#pragma unroll
  for (int mt = 0; mt < 4; ++mt)
#pragma unroll
    for (int r = 0; r < 4; ++r) pool[mt][r] = 0.f;

  int cur = 0;
  for (int s = 0; s < maxlen; ++s) {
    uint2 pu2[4];
    {
      int sn = (s + 2 < myLen) ? (s + 2) : (myLen - 1);
      int t = dir ? (myStart + myLen - 1 - sn) : (myStart + sn);
      const unsigned short* p = pb + (size_t)t * 1024;
#pragma unroll
      for (int mt = 0; mt < 4; ++mt) pu2[mt] = *(const uint2*)(p + mt * 16);
    }

    i32x4 acc[4];
#pragma unroll
    for (int mt = 0; mt < 4; ++mt) acc[mt] = (i32x4){0, 0, 0, 0};
#pragma unroll
    for (int kt = 0; kt < 16; ++kt) {
      long hb = *(const long*)&H[cur][chain][kt * 32 + kgrp * 8];
#pragma unroll
      for (int mt = 0; mt < 4; ++mt)
        acc[mt] = __builtin_amdgcn_mfma_i32_16x16x32_i8(wreg[mt][kt], hb, acc[mt], 0, 0, 0);
    }

    const float msk = (s < myLen) ? 1.f : 0.f;
#pragma unroll
    for (int mt = 0; mt < 4; ++mt) {
      float p2[4];
      p2[0] = __uint_as_float(pu0[mt].x << 16);
      p2[1] = __uint_as_float(pu0[mt].x & 0xFFFF0000u);
      p2[2] = __uint_as_float(pu0[mt].y << 16);
      p2[3] = __uint_as_float(pu0[mt].y & 0xFFFF0000u);
      int q[4];
#pragma unroll
      for (int r = 0; r < 4; ++r) {
        float x2 = fmaf((float)acc[mt][r], DEQ2, p2[r]);
        float e = EXP2F(x2);
        float rc = RCPF(e + 1.f);
        float h = fmaf(-2.f, rc, 1.f);
        pool[mt][r] = fmaf(h, msk, pool[mt][r]);
        q[r] = (int)rintf(fmaf(-254.f, rc, 127.f));
      }
      unsigned int pk = (unsigned)(q[0] & 255) | ((unsigned)(q[1] & 255) << 8) |
                        ((unsigned)(q[2] & 255) << 16) | ((unsigned)q[3] << 24);
      *(unsigned int*)&H[cur ^ 1][chain][dbase + mt * 16 + kgrp * 4] = pk;
    }
    asm volatile("s_waitcnt lgkmcnt(0)" ::: "memory");
    __builtin_amdgcn_s_barrier();
    __builtin_amdgcn_sched_barrier(0);
#pragma unroll
    for (int mt = 0; mt < 4; ++mt) { pu0[mt] = pu1[mt]; pu1[mt] = pu2[mt]; }
    cur ^= 1;
  }

  const float inv = 1.0f / (float)myLen;
  float* op = out + (size_t)sid * OUTW + DPROJ + dir * DLSTM + dbase + kgrp * 4;
#pragma unroll
  for (int mt = 0; mt < 4; ++mt)
    *(float4*)(op + mt * 16) = make_float4(pool[mt][0] * inv, pool[mt][1] * inv,
                                           pool[mt][2] * inv, pool[mt][3] * inv);
}

extern "C" void kernel_launch(void* const* d_in, const int* in_sizes, int n_in,
                              void* d_out, int out_size, void* d_ws, size_t ws_size,
                              hipStream_t stream) {
  const float* x     = (const float*)d_in[0];
  const float* seqs  = (const float*)d_in[1];
  const int*   masks = (const int*)d_in[2];
  const float* Wih_f = (const float*)d_in[3];
  const float* Whh_f = (const float*)d_in[4];
  const float* b_f   = (const float*)d_in[5];
  const float* Wih_b = (const float*)d_in[6];
  const float* Whh_b = (const float*)d_in[7];
  const float* b_b   = (const float*)d_in[8];
  const float* Wx    = (const float*)d_in[9];
  const float* bx    = (const float*)d_in[10];
  float* out = (float*)d_out;

  char* ws = (char*)d_ws;
  const size_t pre_bytes = (size_t)T_N * 1024 * 2;   // 67.1 MB
  const size_t w8_bytes  = (size_t)2 * 512 * 512;    // 0.5 MB
  const size_t wf_bytes  = (size_t)1024 * 128 * 2;   // 256 KB
  unsigned short* pre = (unsigned short*)ws;
  signed char* W8     = (signed char*)(ws + pre_bytes);
  unsigned short* WF  = (unsigned short*)(ws + pre_bytes + w8_bytes);
  int* seg_start      = (int*)(ws + pre_bytes + w8_bytes + wf_bytes);
  int* seg_end        = seg_start + N_SEG;
  int* sorted_ids     = seg_end + N_SEG;

  prep_kernel<<<T_N / 256 + 256 + 16, 256, 0, stream>>>(
      masks, seg_start, seg_end, Whh_f, Whh_b, Wih_f, Wih_b, W8, WF);
  csort_kernel<<<1, 1024, 0, stream>>>(seg_start, seg_end, sorted_ids);
  // pre = (seqs @ [Wih_f;Wih_b]^T + [b_f;b_b]) * 2*log2(e), bf16 out
  gemm_pre_kernel<<<T_N / 64, 256, 0, stream>>>(seqs, WF, b_f, b_b, pre);
  // out[:,0:1024] = x @ Wx^T + bx, f32 out
  gemm_bt_kernel<<<dim3(N_SEG / 128, DPROJ / 128), 256, 0, stream>>>(
      x, Wx, bx, DX, out, OUTW);
  scan_i8t_kernel<<<dim3(N_SEG / 16, 2), 512, 0, stream>>>(
      pre, W8, sorted_ids, seg_start, seg_end, out);
}

// Round 7
// 94.043 us; speedup vs baseline: 1.6379x; 1.3843x over previous
//
#include <hip/hip_runtime.h>
#include <cstdint>
#include <cstddef>

#define T_N    32768
#define N_SEG  2048
#define DSEQ   128
#define DLSTM  512
#define DX     512
#define DPROJ  1024
#define OUTW   2048
#define WSCALE 2873.6827f                 // 127*sqrt(512)
#define LOG2E2 2.8853900817779268f        // 2*log2(e)
#define DEQ2   (2.8853900817779268f/(2873.6827f*127.0f))
#define MAGICF 12582912.0f                // 1.5*2^23: RNE int-round trick

typedef __attribute__((ext_vector_type(8))) short short8;
typedef __attribute__((ext_vector_type(4))) float f32x4;
typedef __attribute__((ext_vector_type(4))) int i32x4;

#if __has_builtin(__builtin_amdgcn_exp2f)
#define EXP2F(x) __builtin_amdgcn_exp2f(x)
#else
#define EXP2F(x) __expf((x) * 0.6931471805599453f)
#endif
#if __has_builtin(__builtin_amdgcn_rcpf)
#define RCPF(x) __builtin_amdgcn_rcpf(x)
#else
#define RCPF(x) (1.0f / (x))
#endif

// packed f32x2 -> bf16x2 (RNE)
__device__ inline unsigned int cvtpk(float a, float b) {
  unsigned int r;
  asm("v_cvt_pk_bf16_f32 %0, %1, %2" : "=v"(r) : "v"(a), "v"(b));
  return r;
}

// ---------------- prep: seg bounds + int8 W_hh K64-frag pack + bf16 W_ih frag pack ----------------
// blocks [0,128): seg bounds. [128,256): W8 pack (K=64 frags). [256,272): WF pack.
__global__ void prep_kernel(const int* __restrict__ masks,
                            int* __restrict__ seg_start, int* __restrict__ seg_end,
                            const float* __restrict__ Whh_f, const float* __restrict__ Whh_b,
                            const float* __restrict__ Wih_f, const float* __restrict__ Wih_b,
                            signed char* __restrict__ W8, unsigned short* __restrict__ WF) {
  const int bx = blockIdx.x;
  if (bx < T_N / 256) {
    int t = bx * 256 + threadIdx.x;
    int m = masks[t];
    if (t == 0 || masks[t - 1] != m) seg_start[m] = t;
    if (t == T_N - 1 || masks[t + 1] != m) seg_end[m] = t + 1;
  } else if (bx < T_N / 256 + 128) {
    // W8 frag id = ((dir*32 + g)*8 + kt)*64 + lane ; n = g*16+(lane&15), k0 = kt*64+(lane>>4)*16
    int id = (bx - T_N / 256) * 256 + threadIdx.x;   // < 32768
    int dir = id >> 14;
    int rem = id & 16383;
    int g = rem >> 9;
    int kt = (rem >> 6) & 7;
    int lane = rem & 63;
    int n = g * 16 + (lane & 15);
    int k0 = kt * 64 + (lane >> 4) * 16;
    const float* W = dir ? Whh_b : Whh_f;
    signed char pkt[16];
#pragma unroll
    for (int j = 0; j < 16; ++j) {
      float w = W[(size_t)n * DLSTM + k0 + j];
      int q = (int)rintf(w * WSCALE);
      q = q > 127 ? 127 : (q < -127 ? -127 : q);
      pkt[j] = (signed char)q;
    }
    i32x4 v;
    __builtin_memcpy(&v, pkt, 16);
    *(i32x4*)&W8[(size_t)id * 16] = v;
  } else {
    // WF: A-frag packed [g(64)][lane(64)][kt(4)][8 bf16]
    int gl = (bx - (T_N / 256 + 128)) * 256 + threadIdx.x;   // < 4096
    int g = gl >> 6, lane = gl & 63;
    int n = g * 16 + (lane & 15);
    const float* src = (n < 512) ? (Wih_f + (size_t)n * DSEQ)
                                 : (Wih_b + (size_t)(n - 512) * DSEQ);
#pragma unroll
    for (int kt = 0; kt < 4; ++kt) {
      int k0 = kt * 32 + (lane >> 4) * 8;
      float4 v0 = *(const float4*)(src + k0);
      float4 v1 = *(const float4*)(src + k0 + 4);
      unsigned int w[4] = {cvtpk(v0.x, v0.y), cvtpk(v0.z, v0.w),
                           cvtpk(v1.x, v1.y), cvtpk(v1.z, v1.w)};
      *(uint4*)&WF[(size_t)((gl << 2) + kt) * 8] = *(uint4*)w;
    }
  }
}

// ---------------- counting sort of segments by length, descending ----------------
__global__ __launch_bounds__(1024) void csort_kernel(const int* __restrict__ seg_start,
                                                     const int* __restrict__ seg_end,
                                                     int* __restrict__ sorted_ids) {
  __shared__ int A_[2048];
  __shared__ int B_[2048];
  const int tid = threadIdx.x;
  for (int i = tid; i < 2048; i += 1024) A_[i] = 0;
  __syncthreads();
  for (int i = tid; i < N_SEG; i += 1024) {
    int len = seg_end[i] - seg_start[i];
    int b = len < 2047 ? len : 2047;
    atomicAdd(&A_[b], 1);
  }
  __syncthreads();
  int* src = A_;
  int* dst = B_;
  for (int d = 1; d < 2048; d <<= 1) {
    for (int i = tid; i < 2048; i += 1024) {
      int v = src[i];
      if (i + d < 2048) v += src[i + d];
      dst[i] = v;
    }
    __syncthreads();
    int* t_ = src; src = dst; dst = t_;
  }
  for (int i = tid; i < 2048; i += 1024)
    dst[i] = (i + 1 < 2048) ? src[i + 1] : 0;
  __syncthreads();
  for (int i = tid; i < N_SEG; i += 1024) {
    int len = seg_end[i] - seg_start[i];
    int b = len < 2047 ? len : 2047;
    int pos = atomicAdd(&dst[b], 1);
    sorted_ids[pos] = i;
  }
}

// ---------------- pre-GEMM: operand-swapped, LDS-free (round-6, validated) ----------------
__global__ __launch_bounds__(256, 2) void gemm_pre_kernel(
    const float* __restrict__ seqs, const unsigned short* __restrict__ WF,
    const float* __restrict__ b_f, const float* __restrict__ b_b,
    unsigned short* __restrict__ pre) {
  const int tid = threadIdx.x;
  const int wave = tid >> 6, lane = tid & 63;
  const int m0 = blockIdx.x * 64;
  const int kgrp = lane >> 4;

  short8 bfr[4][4];   // [mt][kt] seqs B-frags
#pragma unroll
  for (int mt = 0; mt < 4; ++mt) {
    const float* sp = seqs + (size_t)(m0 + mt * 16 + (lane & 15)) * DSEQ;
#pragma unroll
    for (int kt = 0; kt < 4; ++kt) {
      int k0 = kt * 32 + kgrp * 8;
      float4 v0 = *(const float4*)(sp + k0);
      float4 v1 = *(const float4*)(sp + k0 + 4);
      unsigned int w[4] = {cvtpk(v0.x, v0.y), cvtpk(v0.z, v0.w),
                           cvtpk(v1.x, v1.y), cvtpk(v1.z, v1.w)};
      bfr[mt][kt] = *(short8*)w;
    }
  }

#pragma unroll
  for (int pass = 0; pass < 2; ++pass) {
    f32x4 acc[8][4];
#pragma unroll
    for (int nf = 0; nf < 8; ++nf)
#pragma unroll
      for (int mt = 0; mt < 4; ++mt) acc[nf][mt] = (f32x4){0.f, 0.f, 0.f, 0.f};

#pragma unroll
    for (int nf = 0; nf < 8; ++nf) {
      const int g = wave * 16 + pass * 8 + nf;
      short8 wf[4];
      const unsigned short* wp = WF + (size_t)((g * 64 + lane) << 2) * 8;
#pragma unroll
      for (int kt = 0; kt < 4; ++kt) wf[kt] = *(const short8*)(wp + kt * 8);
#pragma unroll
      for (int kt = 0; kt < 4; ++kt)
#pragma unroll
        for (int mt = 0; mt < 4; ++mt)
          acc[nf][mt] = __builtin_amdgcn_mfma_f32_16x16x32_bf16(wf[kt], bfr[mt][kt],
                                                                acc[nf][mt], 0, 0, 0);
    }

#pragma unroll
    for (int nf = 0; nf < 8; ++nf) {
      const int g = wave * 16 + pass * 8 + nf;
      const float* bsrc = (g < 32) ? (b_f + g * 16) : (b_b + (g - 32) * 16);
      float4 bv = *(const float4*)(bsrc + kgrp * 4);
      float bs[4] = {bv.x * LOG2E2, bv.y * LOG2E2, bv.z * LOG2E2, bv.w * LOG2E2};
#pragma unroll
      for (int mt = 0; mt < 4; ++mt) {
        float v0 = fmaf(acc[nf][mt][0], LOG2E2, bs[0]);
        float v1 = fmaf(acc[nf][mt][1], LOG2E2, bs[1]);
        float v2 = fmaf(acc[nf][mt][2], LOG2E2, bs[2]);
        float v3 = fmaf(acc[nf][mt][3], LOG2E2, bs[3]);
        unsigned int w[2] = {cvtpk(v0, v1), cvtpk(v2, v3)};
        size_t m = (size_t)(m0 + mt * 16 + (lane & 15));
        *(uint2*)&pre[m * 1024 + g * 16 + kgrp * 4] = *(uint2*)w;
      }
    }
  }
}

// ---------------- fused: blocks [0,256) = scan ; [256,512) = proj GEMM ----------------
__global__ __launch_bounds__(512, 2) void fused_kernel(
    const unsigned short* __restrict__ pre, const signed char* __restrict__ W8,
    const int* __restrict__ sorted_ids, const int* __restrict__ seg_start_g,
    const int* __restrict__ seg_end_g,
    const float* __restrict__ x, const float* __restrict__ Wx,
    const float* __restrict__ bx, float* __restrict__ out) {
  __shared__ __align__(16) char smem[17408];
  const int bid = blockIdx.x;
  const int tid = threadIdx.x;
  const int wave = tid >> 6, lane = tid & 63;

  if (bid < 256) {
    // ================= scan (i8 K=64 MFMA, counted-wait barrier) =================
    const int bb = bid >> 1, dir = bid & 1;
    const int chain = lane & 15, kgrp = lane >> 4;
    const int dbase = wave * 64;
    signed char (*H)[16][528] = (signed char(*)[16][528])smem;   // [2][16][528]
    int* s_start = (int*)(smem + 16896);
    int* s_len = s_start + 16;
    int* s_sid = s_len + 16;

    if (tid < 16) {
      int sid = sorted_ids[bb * 16 + tid];
      s_sid[tid] = sid;
      int st = seg_start_g[sid];
      s_start[tid] = st;
      s_len[tid] = seg_end_g[sid] - st;
    }
    {  // zero H[0]: 16 rows x 512B, 16B per thread
      int r = tid >> 5, o = (tid & 31) * 16;
      *(i32x4*)&H[0][r][o] = (i32x4){0, 0, 0, 0};
    }
    // weights into registers: 4 mt x 8 kt frags of 16B
    i32x4 wreg[4][8];
    {
      const signed char* wb = W8 + ((size_t)(dir * 32 + wave * 4) * 8 * 64) * 16;
#pragma unroll
      for (int mt = 0; mt < 4; ++mt)
#pragma unroll
        for (int kt = 0; kt < 8; ++kt)
          wreg[mt][kt] = *(const i32x4*)(wb + (size_t)((mt * 8 + kt) * 64 + lane) * 16);
    }
    __syncthreads();

    int maxlen = 0;
#pragma unroll
    for (int c = 0; c < 16; ++c) maxlen = maxlen > s_len[c] ? maxlen : s_len[c];
    const int myLen = s_len[chain], myStart = s_start[chain];
    const int sid = s_sid[chain];

    const unsigned short* __restrict__ pb = pre + (size_t)dir * 512 + dbase + kgrp * 4;

    uint2 pu0[4], pu1[4];
    {
      int t = dir ? (myStart + myLen - 1) : myStart;
      const unsigned short* p = pb + (size_t)t * 1024;
#pragma unroll
      for (int mt = 0; mt < 4; ++mt) pu0[mt] = *(const uint2*)(p + mt * 16);
    }
    {
      int sn = (1 < myLen) ? 1 : (myLen - 1);
      int t = dir ? (myStart + myLen - 1 - sn) : (myStart + sn);
      const unsigned short* p = pb + (size_t)t * 1024;
#pragma unroll
      for (int mt = 0; mt < 4; ++mt) pu1[mt] = *(const uint2*)(p + mt * 16);
    }

    float pool[4][4];
#pragma unroll
    for (int mt = 0; mt < 4; ++mt)
#pragma unroll
      for (int r = 0; r < 4; ++r) pool[mt][r] = 0.f;

    int cur = 0;
    for (int s = 0; s < maxlen; ++s) {
      // prefetch pre for step s+2 (stays in flight across the raw barrier)
      uint2 pu2[4];
      {
        int sn = (s + 2 < myLen) ? (s + 2) : (myLen - 1);
        int t = dir ? (myStart + myLen - 1 - sn) : (myStart + sn);
        const unsigned short* p = pb + (size_t)t * 1024;
#pragma unroll
        for (int mt = 0; mt < 4; ++mt) pu2[mt] = *(const uint2*)(p + mt * 16);
      }

      i32x4 acc[4];
#pragma unroll
      for (int mt = 0; mt < 4; ++mt) acc[mt] = (i32x4){0, 0, 0, 0};
#pragma unroll
      for (int kt = 0; kt < 8; ++kt) {
        i32x4 hb = *(const i32x4*)&H[cur][chain][kt * 64 + kgrp * 16];
#pragma unroll
        for (int mt = 0; mt < 4; ++mt)
          acc[mt] = __builtin_amdgcn_mfma_i32_16x16x64_i8(wreg[mt][kt], hb, acc[mt], 0, 0, 0);
      }

      float rcs[4][4];
#pragma unroll
      for (int mt = 0; mt < 4; ++mt) {
        float p2[4];
        p2[0] = __uint_as_float(pu0[mt].x << 16);
        p2[1] = __uint_as_float(pu0[mt].x & 0xFFFF0000u);
        p2[2] = __uint_as_float(pu0[mt].y << 16);
        p2[3] = __uint_as_float(pu0[mt].y & 0xFFFF0000u);
        unsigned int b[4];
#pragma unroll
        for (int r = 0; r < 4; ++r) {
          float x2 = fmaf((float)acc[mt][r], DEQ2, p2[r]);
          float e = EXP2F(x2);
          float rc = RCPF(e + 1.f);
          rcs[mt][r] = rc;
          float y = fmaf(-254.f, rc, 127.f) + MAGICF;   // RNE round into mantissa
          b[r] = __float_as_uint(y);
        }
        unsigned int pk = (b[0] & 255u) | ((b[1] & 255u) << 8) |
                          ((b[2] & 255u) << 16) | (b[3] << 24);
        *(unsigned int*)&H[cur ^ 1][chain][dbase + mt * 16 + kgrp * 4] = pk;
      }
      // pool update overlaps the LDS-write drain
      const float msk = (s < myLen) ? 1.f : 0.f;
#pragma unroll
      for (int mt = 0; mt < 4; ++mt)
#pragma unroll
        for (int r = 0; r < 4; ++r)
          pool[mt][r] = fmaf(fmaf(-2.f, rcs[mt][r], 1.f), msk, pool[mt][r]);

      asm volatile("s_waitcnt lgkmcnt(0)" ::: "memory");
      __builtin_amdgcn_s_barrier();
      __builtin_amdgcn_sched_barrier(0);
#pragma unroll
      for (int mt = 0; mt < 4; ++mt) { pu0[mt] = pu1[mt]; pu1[mt] = pu2[mt]; }
      cur ^= 1;
    }

    const float inv = 1.0f / (float)myLen;
    float* op = out + (size_t)sid * OUTW + DPROJ + dir * DLSTM + dbase + kgrp * 4;
#pragma unroll
    for (int mt = 0; mt < 4; ++mt)
      *(float4*)(op + mt * 16) = make_float4(pool[mt][0] * inv, pool[mt][1] * inv,
                                             pool[mt][2] * inv, pool[mt][3] * inv);
  } else {
    // ================= proj GEMM: out[:,0:1024] = x @ Wx^T + bx =================
    const int pb_ = bid - 256;
    const int m0 = (pb_ >> 3) * 64, n0 = (pb_ & 7) * 128;
    unsigned short (*As)[40] = (unsigned short(*)[40])smem;              // [64][40]
    unsigned short (*Bs)[40] = (unsigned short(*)[40])(smem + 64 * 40 * 2);  // [128][40]
    const int wm = (wave >> 2) * 32, wn = (wave & 3) * 32;
    const int rowA = lane & 15, kgrp = lane >> 4;
    const int arow = tid >> 3, akc = (tid & 7) * 4;
    const int brow = tid >> 2, bkc = (tid & 3) * 8;

    f32x4 acc[2][2];
#pragma unroll
    for (int i = 0; i < 2; ++i)
#pragma unroll
      for (int j = 0; j < 2; ++j) acc[i][j] = (f32x4){0.f, 0.f, 0.f, 0.f};

    for (int k0 = 0; k0 < DX; k0 += 32) {
      __syncthreads();
      {
        float4 va = *(const float4*)&x[(size_t)(m0 + arow) * DX + k0 + akc];
        unsigned int wa[2] = {cvtpk(va.x, va.y), cvtpk(va.z, va.w)};
        *(uint2*)&As[arow][akc] = *(uint2*)wa;
        const float* bp = Wx + (size_t)(n0 + brow) * DX + k0 + bkc;
        float4 v0 = *(const float4*)bp;
        float4 v1 = *(const float4*)(bp + 4);
        unsigned int wb2[4] = {cvtpk(v0.x, v0.y), cvtpk(v0.z, v0.w),
                               cvtpk(v1.x, v1.y), cvtpk(v1.z, v1.w)};
        *(uint4*)&Bs[brow][bkc] = *(uint4*)wb2;
      }
      __syncthreads();
      short8 af[2], bf[2];
#pragma unroll
      for (int mt = 0; mt < 2; ++mt) af[mt] = *(const short8*)&As[wm + mt * 16 + rowA][kgrp * 8];
#pragma unroll
      for (int nt = 0; nt < 2; ++nt) bf[nt] = *(const short8*)&Bs[wn + nt * 16 + rowA][kgrp * 8];
#pragma unroll
      for (int mt = 0; mt < 2; ++mt)
#pragma unroll
        for (int nt = 0; nt < 2; ++nt)
          acc[mt][nt] = __builtin_amdgcn_mfma_f32_16x16x32_bf16(af[mt], bf[nt], acc[mt][nt], 0, 0, 0);
    }

#pragma unroll
    for (int mt = 0; mt < 2; ++mt)
#pragma unroll
      for (int nt = 0; nt < 2; ++nt) {
        int n = n0 + wn + nt * 16 + rowA;
        float bv = bx[n];
#pragma unroll
        for (int r = 0; r < 4; ++r) {
          int m = m0 + wm + mt * 16 + kgrp * 4 + r;
          out[(size_t)m * OUTW + n] = acc[mt][nt][r] + bv;
        }
      }
  }
}

extern "C" void kernel_launch(void* const* d_in, const int* in_sizes, int n_in,
                              void* d_out, int out_size, void* d_ws, size_t ws_size,
                              hipStream_t stream) {
  const float* x     = (const float*)d_in[0];
  const float* seqs  = (const float*)d_in[1];
  const int*   masks = (const int*)d_in[2];
  const float* Wih_f = (const float*)d_in[3];
  const float* Whh_f = (const float*)d_in[4];
  const float* b_f   = (const float*)d_in[5];
  const float* Wih_b = (const float*)d_in[6];
  const float* Whh_b = (const float*)d_in[7];
  const float* b_b   = (const float*)d_in[8];
  const float* Wx    = (const float*)d_in[9];
  const float* bx    = (const float*)d_in[10];
  float* out = (float*)d_out;

  char* ws = (char*)d_ws;
  const size_t pre_bytes = (size_t)T_N * 1024 * 2;   // 67.1 MB
  const size_t w8_bytes  = (size_t)2 * 512 * 512;    // 0.5 MB
  const size_t wf_bytes  = (size_t)1024 * 128 * 2;   // 256 KB
  unsigned short* pre = (unsigned short*)ws;
  signed char* W8     = (signed char*)(ws + pre_bytes);
  unsigned short* WF  = (unsigned short*)(ws + pre_bytes + w8_bytes);
  int* seg_start      = (int*)(ws + pre_bytes + w8_bytes + wf_bytes);
  int* seg_end        = seg_start + N_SEG;
  int* sorted_ids     = seg_end + N_SEG;

  prep_kernel<<<T_N / 256 + 128 + 16, 256, 0, stream>>>(
      masks, seg_start, seg_end, Whh_f, Whh_b, Wih_f, Wih_b, W8, WF);
  csort_kernel<<<1, 1024, 0, stream>>>(seg_start, seg_end, sorted_ids);
  gemm_pre_kernel<<<T_N / 64, 256, 0, stream>>>(seqs, WF, b_f, b_b, pre);
  fused_kernel<<<512, 512, 0, stream>>>(pre, W8, sorted_ids, seg_start, seg_end,
                                        x, Wx, bx, out);
}